// Round 2
// baseline (2487.630 us; speedup 1.0000x reference)
//
#include <hip/hip_runtime.h>
#include <math.h>

#define B_    4096
#define L_    16
#define E_    50
#define EP_   64
#define H_    512
#define G4_   2048
#define V_    128
#define VIS_  2048

typedef unsigned short ushortT;
typedef ushortT ushort8 __attribute__((ext_vector_type(8)));
typedef ushortT ushort4v __attribute__((ext_vector_type(4)));
typedef short   short8  __attribute__((ext_vector_type(8)));
typedef float   f32x4   __attribute__((ext_vector_type(4)));

__device__ __forceinline__ ushortT f2bf(float f) {
  union { float f; unsigned u; } v; v.f = f;
  unsigned u = v.u;
  u += 0x7fffu + ((u >> 16) & 1u);
  return (ushortT)(u >> 16);
}
__device__ __forceinline__ float bf2f(ushortT h) {
  union { unsigned u; float f; } v; v.u = ((unsigned)h) << 16;
  return v.f;
}
__device__ __forceinline__ float sigm(float x) { return 1.f / (1.f + __expf(-x)); }
__device__ __forceinline__ float tanh_f(float x) { return 1.f - 2.f / (__expf(2.f * x) + 1.f); }

// ================================================================ mega prep (grid 30832 x 256)
__global__ void prep_all_k(const float* __restrict__ visual, const int* __restrict__ text,
                           const float* __restrict__ emb,
                           const float* __restrict__ W_ih, const float* __restrict__ W_hh,
                           const float* __restrict__ b_ih, const float* __restrict__ b_hh,
                           const float* __restrict__ W_enc, const float* __restrict__ W_out,
                           const float* __restrict__ W_vis,
                           ushortT* __restrict__ xs_enc, ushortT* __restrict__ xs_dec,
                           ushortT* __restrict__ Wfrag, ushortT* __restrict__ Woutfrag,
                           float* __restrict__ biasc, float* __restrict__ biasc0,
                           ushortT* __restrict__ Wvisbf, ushortT* __restrict__ Wencbf,
                           ushortT* __restrict__ visbf, int* __restrict__ lens,
                           unsigned* __restrict__ barcnt) {
  int bid = blockIdx.x, tid = threadIdx.x;
  if (bid < 16384) {
    int idx = bid * 256 + tid;
    int e = idx & 63, r = idx >> 6, b = r % B_, t = r / B_;
    ushortT ve = 0, vd = 0;
    if (e < E_) {
      int ie = text[b * L_ + t];
      int id = (t == 0) ? 0 : text[b * L_ + t - 1];
      ve = f2bf(emb[ie * E_ + e]);
      vd = f2bf(emb[id * E_ + e]);
    }
    xs_enc[idx] = ve; xs_dec[idx] = vd;
  } else if (bid < 16960) {                           // Wfrag: 32 slices x 18 ks x 4 ni x 64 ln
    int idx8 = (bid - 16384) * 256 + tid;
    int s = idx8 / 4608;
    int rem = idx8 - s * 4608;
    int ks = rem >> 8;
    int rem2 = rem & 255;
    int ni = rem2 >> 6, ln = rem2 & 63;
    int row = s * 64 + ni * 16 + (ln & 15);
    int kc = (ln >> 4) * 8;
    int j = row >> 2, qg = row & 3;
    int srow = qg * H_ + j;
    ushort8 val;
    if (ks < 16) {
      const float* src = W_hh + (size_t)srow * H_ + ks * 32 + kc;
#pragma unroll
      for (int x = 0; x < 8; ++x) val[x] = f2bf(src[x]);
    } else {
      int kb = (ks - 16) * 32 + kc;
#pragma unroll
      for (int x = 0; x < 8; ++x)
        val[x] = (kb + x < E_) ? f2bf(W_ih[(size_t)srow * E_ + kb + x]) : (ushortT)0;
    }
    *(ushort8*)(&Wfrag[(size_t)idx8 * 8]) = val;
  } else if (bid < 16992) {                           // Woutfrag
    int idx8 = (bid - 16960) * 256 + tid;
    int ks = idx8 >> 9;
    int rem = idx8 & 511;
    int nf = rem >> 6, ln = rem & 63;
    int row = nf * 16 + (ln & 15);
    int kc = ks * 32 + (ln >> 4) * 8;
    const float* src = W_out + (size_t)row * H_ + kc;
    ushort8 val;
#pragma unroll
    for (int x = 0; x < 8; ++x) val[x] = f2bf(src[x]);
    *(ushort8*)(&Woutfrag[(size_t)idx8 * 8]) = val;
  } else if (bid < 21088) {
    int idx = (bid - 16992) * 256 + tid;
    Wvisbf[idx] = f2bf(W_vis[idx]);
  } else if (bid < 22112) {
    int idx = (bid - 21088) * 256 + tid;
    Wencbf[idx] = f2bf(W_enc[idx]);
  } else if (bid < 30304) {
    int i = (bid - 22112) * 256 + tid;
    float4 v = ((const float4*)visual)[i];
    ushort4v o;
    o[0] = f2bf(v.x); o[1] = f2bf(v.y); o[2] = f2bf(v.z); o[3] = f2bf(v.w);
    ((ushort4v*)visbf)[i] = o;
  } else if (bid < 30320) {
    if (bid == 30304 && tid < 4) barcnt[tid] = 0u;
    int b = (bid - 30304) * 256 + tid;
    int c = 0;
    for (int t = 0; t < L_; ++t) c += (text[b * L_ + t] != 0) ? 1 : 0;
    lens[b] = c;
  } else {                                            // biasc / biasc0, one wave per gate-row
    int wave = tid >> 6, lane = tid & 63;
    int p = (bid - 30320) * 4 + wave;
    int j = p >> 2, q = p & 3, o = q * H_ + j;
    const float* wr = W_hh + (size_t)o * H_;
    float rs = 0.f;
#pragma unroll
    for (int k = 0; k < H_ / 64; ++k) rs += wr[lane + k * 64];
#pragma unroll
    for (int d = 1; d < 64; d <<= 1) rs += __shfl_xor(rs, d);
    if (lane == 0) {
      float base = b_ih[o] + b_hh[o];
      biasc[p] = base;
      biasc0[p] = base + 0.1f * rs;
    }
  }
}

// ================================================================ gemm_ws2: 512 threads, 128x128 tile
__global__ __launch_bounds__(512, 2)
void gemm_ws2_k(const ushortT* __restrict__ A, int lda,
                const ushortT* __restrict__ Bp, int ldb, int kchunk,
                float* __restrict__ Cf, ushortT* __restrict__ Cb,
                int ldc, int Mtot) {
  __shared__ ushortT wl[2][16384];            // 2 x 32 KB
  const int tid = threadIdx.x;
  const int n0 = blockIdx.x * 128;
  const int m0 = blockIdx.y * 128;
  const int lane = tid & 63, wave = tid >> 6;
  const int q = lane >> 4, r = lane & 15;
  const int ak = q * 8;
  const int wrow = m0 + wave * 16;
  const int kbeg = blockIdx.z * kchunk;
  const int nchunks = kchunk >> 7;

  auto stage = [&](int kb, int buf) {
#pragma unroll
    for (int i = 0; i < 4; ++i) {
      int u = tid + i * 512;
      int f = u >> 6, l = u & 63;
      int kk = f >> 3, nn = f & 7;
      int row = n0 + nn * 16 + (l & 15);
      int kc = kb + kk * 32 + (l >> 4) * 8;
      *(ushort8*)(&wl[buf][((kk * 8 + nn) * 64 + l) * 8]) =
          *(const ushort8*)(&Bp[(size_t)row * ldb + kc]);
    }
  };

  f32x4 acc[8];
#pragma unroll
  for (int nn = 0; nn < 8; ++nn)
#pragma unroll
    for (int x = 0; x < 4; ++x) acc[nn][x] = 0.f;

  stage(kbeg, 0);
  __syncthreads();
  for (int ch = 0; ch < nchunks; ++ch) {
    int buf = ch & 1;
    if (ch + 1 < nchunks) stage(kbeg + (ch + 1) * 128, buf ^ 1);
    int kb = kbeg + ch * 128;
#pragma unroll
    for (int kk = 0; kk < 4; ++kk) {
      short8 a = *(const short8*)(&A[(size_t)(wrow + r) * lda + kb + kk * 32 + ak]);
#pragma unroll
      for (int nn = 0; nn < 8; ++nn) {
        short8 b = *(const short8*)(&wl[buf][((kk * 8 + nn) * 64 + lane) * 8]);
        acc[nn] = __builtin_amdgcn_mfma_f32_16x16x32_bf16(a, b, acc[nn], 0, 0, 0);
      }
    }
    __syncthreads();
  }

  if (Cb) {
#pragma unroll
    for (int nn = 0; nn < 8; ++nn) {
      int col = n0 + nn * 16 + r;
#pragma unroll
      for (int rr = 0; rr < 4; ++rr)
        Cb[(size_t)(wrow + q * 4 + rr) * ldc + col] = f2bf(acc[nn][rr]);
    }
  } else {
    float* Cz = Cf + (size_t)blockIdx.z * Mtot * ldc;
#pragma unroll
    for (int nn = 0; nn < 8; ++nn) {
      int col = n0 + nn * 16 + r;
#pragma unroll
      for (int rr = 0; rr < 4; ++rr)
        Cz[(size_t)(wrow + q * 4 + rr) * ldc + col] = acc[nn][rr];
    }
  }
}

// ================================================================ reduce partials + bias/relu + rownorm
__global__ void reduce_norm_k(const float* __restrict__ parts, int nparts,
                              const float* __restrict__ bias, int relu,
                              ushortT* __restrict__ outb, ushortT* __restrict__ outc) {
  int b = blockIdx.x, tid = threadIdx.x;
  float v[2];
  float ss = 0.f;
#pragma unroll
  for (int l = 0; l < 2; ++l) {
    int i = tid + l * 256;
    float s = 0.f;
    for (int p = 0; p < nparts; ++p)
      s += parts[(size_t)p * B_ * H_ + (size_t)b * H_ + i];
    if (bias) s += bias[i];
    if (relu) s = fmaxf(s, 0.f);
    v[l] = s;
    ss += s * s;
  }
  __shared__ float red[256];
  red[tid] = ss; __syncthreads();
  for (int st = 128; st > 0; st >>= 1) { if (tid < st) red[tid] += red[tid + st]; __syncthreads(); }
  float inv = 1.f / sqrtf(red[0]);
#pragma unroll
  for (int l = 0; l < 2; ++l) {
    int i = tid + l * 256;
    float x = v[l] * inv;
    ushortT xb = f2bf(x);
    outb[(size_t)b * H_ + i] = xb;
    if (outc) outc[(size_t)b * H_ + i] = xb;
  }
}

// ================================================================ LDS-free NLL for one 16-row unit;
// accumulates per-row loss into lacc[4] (valid on all lanes of each 16-lane quarter).
__device__ __forceinline__ void nll_step(const ushortT* __restrict__ h,
                                         const ushortT* __restrict__ Woutfrag,
                                         const int* __restrict__ text,
                                         int row0, int t, int lane, float* lacc) {
  const int q = lane >> 4, r = lane & 15;
  const int ak = q * 8;
  float m[4], s[4], tl[4];
  int tgt[4];
#pragma unroll
  for (int rr = 0; rr < 4; ++rr) {
    m[rr] = -1e30f; s[rr] = 0.f; tl[rr] = 0.f;
    tgt[rr] = text[(row0 + q * 4 + rr) * L_ + t];
  }
#pragma unroll
  for (int gg = 0; gg < 2; ++gg) {
    f32x4 acc[4];
#pragma unroll
    for (int nf = 0; nf < 4; ++nf)
#pragma unroll
      for (int x = 0; x < 4; ++x) acc[nf][x] = 0.f;
    for (int ks = 0; ks < 16; ++ks) {
      short8 a = *(const short8*)(&h[(size_t)(row0 + r) * H_ + ks * 32 + ak]);
#pragma unroll
      for (int nf = 0; nf < 4; ++nf) {
        short8 b = *(const short8*)(&Woutfrag[((ks * 8 + gg * 4 + nf) * 64 + lane) * 8]);
        acc[nf] = __builtin_amdgcn_mfma_f32_16x16x32_bf16(a, b, acc[nf], 0, 0, 0);
      }
    }
#pragma unroll
    for (int rr = 0; rr < 4; ++rr) {
      float gm = fmaxf(fmaxf(acc[0][rr], acc[1][rr]), fmaxf(acc[2][rr], acc[3][rr]));
      float nm = fmaxf(m[rr], gm);
      float sc = __expf(m[rr] - nm);
      s[rr] = s[rr] * sc + __expf(acc[0][rr] - nm) + __expf(acc[1][rr] - nm)
            + __expf(acc[2][rr] - nm) + __expf(acc[3][rr] - nm);
      m[rr] = nm;
      int tg = tgt[rr];
      if ((tg >> 6) == gg && r == (tg & 15)) {
        int nfl = (tg >> 4) & 3;
        float vv = (nfl == 0) ? acc[0][rr] : (nfl == 1) ? acc[1][rr]
                 : (nfl == 2) ? acc[2][rr] : acc[3][rr];
        tl[rr] = vv;
      }
    }
  }
#pragma unroll
  for (int rr = 0; rr < 4; ++rr) {
#pragma unroll
    for (int d = 1; d < 16; d <<= 1) {
      float om = __shfl_xor(m[rr], d);
      float os = __shfl_xor(s[rr], d);
      float M = fmaxf(m[rr], om);
      s[rr] = s[rr] * __expf(m[rr] - M) + os * __expf(om - M);
      m[rr] = M;
    }
    float lse = m[rr] + __logf(s[rr]);
    float tlb = __shfl(tl[rr], (lane & 48) + (tgt[rr] & 15));
    lacc[rr] += lse - tlb;
  }
}

// ================================================================ persistent LSTM sequence kernel.
// Grid 256 = 16 gate-slices (g) x 16 row-pairs (p); 512 threads; 1 block/CU (128 KB LDS).
// W_hh slice lives in LDS for all 16 steps; c-state lives in registers; grid barrier per step.
// mode 0 = encoder (sel capture, h0 folded in biasc0, c0=0.1); mode 1 = decoder (fused NLL).
__global__ __launch_bounds__(512, 2)
void lstm_seq_k(const ushortT* __restrict__ Wfrag_g, const ushortT* __restrict__ xs,
                const float* __restrict__ biasc, const float* __restrict__ biasc0,
                ushortT* __restrict__ hb0, ushortT* __restrict__ hb1,
                const ushortT* __restrict__ hinit,
                ushortT* __restrict__ sel, const int* __restrict__ lens,
                const ushortT* __restrict__ Woutfrag, const int* __restrict__ text,
                float* __restrict__ out, unsigned* __restrict__ barcnt, int mode) {
  __shared__ __align__(16) ushortT wlds[65536];   // 128 KB: ks 0..15 part of the W slice
  const int tid = threadIdx.x;
  const int lane = tid & 63, wave = tid >> 6;
  const int q = lane >> 4, r = lane & 15;
  const int ak = q * 8;
  const int g = blockIdx.x >> 4;                 // gate slice 0..15
  const int p = blockIdx.x & 15;                 // row pair 0..15 (XCD = p & 7)
  const int row0g = p * 256 + wave * 32;
  const int row1g = row0g + 16;
  const ushortT* Wbase = Wfrag_g + (size_t)(2 * g) * 36864;

  // stage W_hh halves into LDS (layout-preserving copy of elements [0,32768) of each half)
  {
    const ushort8* s0 = (const ushort8*)(Wbase);
    const ushort8* s1 = (const ushort8*)(Wbase + 36864);
    ushort8* d0 = (ushort8*)(wlds);
    ushort8* d1 = (ushort8*)(wlds + 32768);
#pragma unroll
    for (int k = 0; k < 8; ++k) {
      d0[tid + k * 512] = s0[tid + k * 512];
      d1[tid + k * 512] = s1[tid + k * 512];
    }
  }

  // c-state in registers (one value per lane per (grp,nn))
  float creg[2][8];
#pragma unroll
  for (int grp = 0; grp < 2; ++grp) {
    int rowc = (grp ? row1g : row0g) + q * 4 + (r & 3);
#pragma unroll
    for (int nn = 0; nn < 8; ++nn) {
      int j = g * 32 + nn * 4 + (r >> 2);
      creg[grp][nn] = (mode == 0) ? 0.1f : bf2f(hinit[(size_t)rowc * H_ + j]);
    }
  }
  float lacc[4] = {0.f, 0.f, 0.f, 0.f};
  const int nllrow0 = p * 256 + g * 16;
  __syncthreads();

  for (int t = 0; t < L_; ++t) {
    // fused NLL on h_{t-1} (decoder, wave 0 only) — overlaps other waves' GEMM
    if (mode == 1 && wave == 0 && t > 0)
      nll_step((t & 1) ? hb0 : hb1, Woutfrag, text, nllrow0, t - 1, lane, lacc);

    const ushortT* hs = (t == 0) ? hinit : ((t & 1) ? hb0 : hb1);
    const ushortT* xst = xs + (size_t)t * B_ * EP_;

    f32x4 acc0[8], acc1[8];
#pragma unroll
    for (int nn = 0; nn < 8; ++nn)
#pragma unroll
      for (int x = 0; x < 4; ++x) { acc0[nn][x] = 0.f; acc1[nn][x] = 0.f; }

    if (mode == 1 || t > 0) {
      for (int ks = 0; ks < 16; ++ks) {
        short8 a0 = *(const short8*)(&hs[(size_t)(row0g + r) * H_ + ks * 32 + ak]);
        short8 a1 = *(const short8*)(&hs[(size_t)(row1g + r) * H_ + ks * 32 + ak]);
#pragma unroll
        for (int nn = 0; nn < 8; ++nn) {
          short8 b = *(const short8*)(&wlds[(nn >> 2) * 32768 + ((ks * 4 + (nn & 3)) * 64 + lane) * 8]);
          acc0[nn] = __builtin_amdgcn_mfma_f32_16x16x32_bf16(a0, b, acc0[nn], 0, 0, 0);
          acc1[nn] = __builtin_amdgcn_mfma_f32_16x16x32_bf16(a1, b, acc1[nn], 0, 0, 0);
        }
      }
    }
#pragma unroll
    for (int kx = 0; kx < 2; ++kx) {
      short8 a0 = *(const short8*)(&xst[(size_t)(row0g + r) * EP_ + kx * 32 + ak]);
      short8 a1 = *(const short8*)(&xst[(size_t)(row1g + r) * EP_ + kx * 32 + ak]);
#pragma unroll
      for (int nn = 0; nn < 8; ++nn) {
        short8 b = *(const short8*)(&Wbase[(size_t)(nn >> 2) * 36864 + 32768 +
                                           ((kx * 4 + (nn & 3)) * 64 + lane) * 8]);
        acc0[nn] = __builtin_amdgcn_mfma_f32_16x16x32_bf16(a0, b, acc0[nn], 0, 0, 0);
        acc1[nn] = __builtin_amdgcn_mfma_f32_16x16x32_bf16(a1, b, acc1[nn], 0, 0, 0);
      }
    }

    // epilogue: shuffle-transpose + cell update
    const float* bcur = (mode == 0 && t == 0) ? biasc0 : biasc;
    ushortT* hout = (t & 1) ? hb1 : hb0;
#pragma unroll
    for (int grp = 0; grp < 2; ++grp) {
      int rowbase = grp ? row1g : row0g;
#pragma unroll
      for (int nn = 0; nn < 8; ++nn) {
        f32x4 av = grp ? acc1[nn] : acc0[nn];
        float v0 = av[0], v1 = av[1], v2 = av[2], v3 = av[3];
        float e0 = __shfl_xor(v0, 2), e1 = __shfl_xor(v1, 2),
              e2 = __shfl_xor(v2, 2), e3 = __shfl_xor(v3, 2);
        float b0, b1, b2, b3;
        if (r & 2) { b0 = e2; b1 = e3; b2 = v2; b3 = v3; }
        else       { b0 = v0; b1 = v1; b2 = e0; b3 = e1; }
        float f0 = __shfl_xor(b0, 1), f1 = __shfl_xor(b1, 1),
              f2 = __shfl_xor(b2, 1), f3 = __shfl_xor(b3, 1);
        float g0, g1, g2, g3;
        if (r & 1) { g0 = f1; g1 = b1; g2 = f3; g3 = b3; }
        else       { g0 = b0; g1 = f0; g2 = b2; g3 = f2; }
        int row = rowbase + q * 4 + (r & 3);
        int j = g * 32 + nn * 4 + (r >> 2);
        f32x4 bb = *(const f32x4*)(&bcur[j * 4]);
        float si = sigm(g0 + bb[0]);
        float sf = sigm(g1 + bb[1]);
        float tg = tanh_f(g2 + bb[2]);
        float so = sigm(g3 + bb[3]);
        float cn = sf * creg[grp][nn] + si * tg;
        creg[grp][nn] = cn;
        float hn = so * tanh_f(cn);
        ushortT hb16 = f2bf(hn);
        hout[(size_t)row * H_ + j] = hb16;
        if (mode == 0) {
          int len = lens[row];
          int eff = (len == 0) ? L_ : len;
          if (t == eff - 1) sel[(size_t)row * H_ + j] = hb16;
        }
      }
    }

    // grid barrier (monotonic counter, device scope)
    __syncthreads();
    if (tid == 0) {
      __hip_atomic_fetch_add(barcnt, 1u, __ATOMIC_ACQ_REL, __HIP_MEMORY_SCOPE_AGENT);
      unsigned tgtv = 256u * (unsigned)(t + 1);
      while (__hip_atomic_load(barcnt, __ATOMIC_ACQUIRE, __HIP_MEMORY_SCOPE_AGENT) < tgtv)
        __builtin_amdgcn_s_sleep(2);
      __threadfence();
    }
    __syncthreads();
  }

  // final NLL on h_15 + single loss store
  if (mode == 1 && wave == 0) {
    nll_step(hb1, Woutfrag, text, nllrow0, L_ - 1, lane, lacc);
#pragma unroll
    for (int rr = 0; rr < 4; ++rr)
      if (r == 0) out[nllrow0 + q * 4 + rr] = lacc[rr] * (1.f / (float)L_);
  }
}

// ================================================================ softmax / transpose
__global__ __launch_bounds__(256)
void softmax_bf_rows_k(ushortT* __restrict__ P) {
  int rr = blockIdx.x, tid = threadIdx.x;
  ushortT* row = P + (size_t)rr * B_;
  float xv[16];
  float m = -1e30f;
#pragma unroll
  for (int l = 0; l < 16; ++l) { float v = bf2f(row[tid + l * 256]); xv[l] = v; m = fmaxf(m, v); }
  __shared__ float red[256];
  red[tid] = m; __syncthreads();
  for (int st = 128; st > 0; st >>= 1) { if (tid < st) red[tid] = fmaxf(red[tid], red[tid + st]); __syncthreads(); }
  m = red[0]; __syncthreads();
  float s = 0.f;
#pragma unroll
  for (int l = 0; l < 16; ++l) { float e = __expf(xv[l] - m); xv[l] = e; s += e; }
  red[tid] = s; __syncthreads();
  for (int st = 128; st > 0; st >>= 1) { if (tid < st) red[tid] += red[tid + st]; __syncthreads(); }
  float inv = 1.f / red[0];
#pragma unroll
  for (int l = 0; l < 16; ++l) row[tid + l * 256] = f2bf(xv[l] * inv);
}

__global__ void transpose_bf_k(const ushortT* __restrict__ in, ushortT* __restrict__ out,
                               int R, int Ccols) {
  __shared__ ushortT tile[32][33];
  int c0 = blockIdx.x * 32, r0 = blockIdx.y * 32;
  int tx = threadIdx.x & 31, ty = threadIdx.x >> 5;
  for (int i = ty; i < 32; i += 8) tile[i][tx] = in[(size_t)(r0 + i) * Ccols + c0 + tx];
  __syncthreads();
  for (int i = ty; i < 32; i += 8) out[(size_t)(c0 + i) * R + r0 + tx] = tile[tx][i];
}

// ================================================================ launch
extern "C" void kernel_launch(void* const* d_in, const int* in_sizes, int n_in,
                              void* d_out, int out_size, void* d_ws, size_t ws_size,
                              hipStream_t stream) {
  const float* visual = (const float*)d_in[0];
  const int*   text   = (const int*)  d_in[1];
  const float* emb    = (const float*)d_in[2];
  const float* W_ih   = (const float*)d_in[3];
  const float* W_hh   = (const float*)d_in[4];
  const float* b_ih   = (const float*)d_in[5];
  const float* b_hh   = (const float*)d_in[6];
  const float* W_enc  = (const float*)d_in[7];
  const float* b_enc  = (const float*)d_in[8];
  const float* W_out  = (const float*)d_in[9];
  const float* W_vis  = (const float*)d_in[10];
  float* out = (float*)d_out;

  char* w = (char*)d_ws;
  auto alloc = [&](size_t bytes) { char* p = w; w += (bytes + 255) & ~(size_t)255; return p; };
  ushortT* xs_enc   = (ushortT*)alloc((size_t)L_ * B_ * EP_ * 2);
  ushortT* xs_dec   = (ushortT*)alloc((size_t)L_ * B_ * EP_ * 2);
  ushortT* Wfrag    = (ushortT*)alloc((size_t)32 * 18 * 4 * 64 * 8 * 2);
  ushortT* Woutfrag = (ushortT*)alloc((size_t)16 * 8 * 64 * 8 * 2);
  float*   biasc    = (float*)  alloc((size_t)G4_ * 4);
  float*   biasc0   = (float*)  alloc((size_t)G4_ * 4);
  ushortT* Wvisbf   = (ushortT*)alloc((size_t)H_ * VIS_ * 2);
  ushortT* Wencbf   = (ushortT*)alloc((size_t)H_ * H_ * 2);
  ushortT* visbf    = (ushortT*)alloc((size_t)B_ * VIS_ * 2);
  ushortT* henc0    = (ushortT*)alloc((size_t)B_ * H_ * 2);
  ushortT* henc1    = (ushortT*)alloc((size_t)B_ * H_ * 2);
  ushortT* selbf    = (ushortT*)alloc((size_t)B_ * H_ * 2);
  ushortT* vbf      = (ushortT*)alloc((size_t)B_ * H_ * 2);
  ushortT* tencbf   = (ushortT*)alloc((size_t)B_ * H_ * 2);
  ushortT* Pbf      = (ushortT*)alloc((size_t)B_ * B_ * 2);
  ushortT* Vtbf     = (ushortT*)alloc((size_t)H_ * B_ * 2);
  ushortT* hdec0    = (ushortT*)alloc((size_t)B_ * H_ * 2);
  ushortT* hdec1    = (ushortT*)alloc((size_t)B_ * H_ * 2);
  ushortT* hdec2    = (ushortT*)alloc((size_t)B_ * H_ * 2);
  int*     lens     = (int*)    alloc((size_t)B_ * 4);
  unsigned* barcnt  = (unsigned*)alloc(256);
  float*   parts    = (float*)  alloc((size_t)4 * B_ * H_ * 4);

  // ---- mega prep (also zeroes barrier counters)
  prep_all_k<<<dim3(30832), dim3(256), 0, stream>>>(
      visual, text, emb, W_ih, W_hh, b_ih, b_hh, W_enc, W_out, W_vis,
      xs_enc, xs_dec, Wfrag, Woutfrag, biasc, biasc0,
      Wvisbf, Wencbf, visbf, lens, barcnt);

  // ---- visual projection (z=2, kchunk=1024) + rownorm -> vbf
  gemm_ws2_k<<<dim3(H_ / 128, B_ / 128, 2), dim3(512), 0, stream>>>(
      visbf, VIS_, Wvisbf, VIS_, 1024, parts, nullptr, H_, B_);
  reduce_norm_k<<<dim3(B_), dim3(256), 0, stream>>>(parts, 2, nullptr, 0, vbf, nullptr);

  // ---- encoder LSTM: one persistent cooperative kernel, 16 steps
  {
    const ushortT* xsp = xs_enc; const float* bcp = biasc; const float* bc0p = biasc0;
    ushortT* h0p = henc0; ushortT* h1p = henc1; const ushortT* hip_ = nullptr;
    ushortT* selp = selbf; const int* lenp = lens;
    const ushortT* wop = nullptr; const int* txp = nullptr; float* outp = nullptr;
    unsigned* bcnt = barcnt; int md = 0;
    void* args[] = {(void*)&Wfrag, (void*)&xsp, (void*)&bcp, (void*)&bc0p,
                    (void*)&h0p, (void*)&h1p, (void*)&hip_, (void*)&selp, (void*)&lenp,
                    (void*)&wop, (void*)&txp, (void*)&outp, (void*)&bcnt, (void*)&md};
    hipLaunchCooperativeKernel(reinterpret_cast<const void*>(lstm_seq_k),
                               dim3(256), dim3(512), args, 0, stream);
  }

  // ---- enc linear (z=2, kchunk=256) + bias/relu/rownorm -> tencbf
  gemm_ws2_k<<<dim3(H_ / 128, B_ / 128, 2), dim3(512), 0, stream>>>(
      selbf, H_, Wencbf, H_, 256, parts, nullptr, H_, B_);
  reduce_norm_k<<<dim3(B_), dim3(256), 0, stream>>>(parts, 2, b_enc, 1, tencbf, nullptr);

  // ---- attention
  gemm_ws2_k<<<dim3(B_ / 128, B_ / 128, 1), dim3(512), 0, stream>>>(
      tencbf, H_, vbf, H_, 512, nullptr, Pbf, B_, B_);
  softmax_bf_rows_k<<<dim3(B_), dim3(256), 0, stream>>>(Pbf);
  transpose_bf_k<<<dim3(H_ / 32, B_ / 32), dim3(256), 0, stream>>>(vbf, Vtbf, B_, H_);
  gemm_ws2_k<<<dim3(H_ / 128, B_ / 128, 4), dim3(512), 0, stream>>>(
      Pbf, B_, Vtbf, B_, 1024, parts, nullptr, H_, B_);
  reduce_norm_k<<<dim3(B_), dim3(256), 0, stream>>>(parts, 4, nullptr, 0, hdec0, nullptr);

  // ---- decoder LSTM + fused NLL: one persistent cooperative kernel, 16 steps
  {
    const ushortT* xsp = xs_dec; const float* bcp = biasc; const float* bc0p = biasc0;
    ushortT* h0p = hdec1; ushortT* h1p = hdec2; const ushortT* hip_ = hdec0;
    ushortT* selp = nullptr; const int* lenp = nullptr;
    const ushortT* wop = Woutfrag; const int* txp = text; float* outp = out;
    unsigned* bcnt = barcnt + 1; int md = 1;
    void* args[] = {(void*)&Wfrag, (void*)&xsp, (void*)&bcp, (void*)&bc0p,
                    (void*)&h0p, (void*)&h1p, (void*)&hip_, (void*)&selp, (void*)&lenp,
                    (void*)&wop, (void*)&txp, (void*)&outp, (void*)&bcnt, (void*)&md};
    hipLaunchCooperativeKernel(reinterpret_cast<const void*>(lstm_seq_k),
                               dim3(256), dim3(512), args, 0, stream);
  }
}

// Round 3
// 1327.724 us; speedup vs baseline: 1.8736x; 1.8736x over previous
//
#include <hip/hip_runtime.h>
#include <math.h>

#define B_    4096
#define L_    16
#define E_    50
#define EP_   64
#define H_    512
#define G4_   2048
#define V_    128
#define VIS_  2048

typedef unsigned short ushortT;
typedef ushortT ushort8 __attribute__((ext_vector_type(8)));
typedef ushortT ushort4v __attribute__((ext_vector_type(4)));
typedef short   short8  __attribute__((ext_vector_type(8)));
typedef float   f32x4   __attribute__((ext_vector_type(4)));

__device__ __forceinline__ ushortT f2bf(float f) {
  union { float f; unsigned u; } v; v.f = f;
  unsigned u = v.u;
  u += 0x7fffu + ((u >> 16) & 1u);
  return (ushortT)(u >> 16);
}
__device__ __forceinline__ float bf2f(ushortT h) {
  union { unsigned u; float f; } v; v.u = ((unsigned)h) << 16;
  return v.f;
}
__device__ __forceinline__ float sigm(float x) { return 1.f / (1.f + __expf(-x)); }
__device__ __forceinline__ float tanh_f(float x) { return 1.f - 2.f / (__expf(2.f * x) + 1.f); }

// ================================================================ mega prep (grid 30832 x 256)
__global__ void prep_all_k(const float* __restrict__ visual, const int* __restrict__ text,
                           const float* __restrict__ emb,
                           const float* __restrict__ W_ih, const float* __restrict__ W_hh,
                           const float* __restrict__ b_ih, const float* __restrict__ b_hh,
                           const float* __restrict__ W_enc, const float* __restrict__ W_out,
                           const float* __restrict__ W_vis,
                           ushortT* __restrict__ xs_enc, ushortT* __restrict__ xs_dec,
                           ushortT* __restrict__ Wfrag, ushortT* __restrict__ Woutfrag,
                           float* __restrict__ biasc, float* __restrict__ biasc0,
                           ushortT* __restrict__ Wvisbf, ushortT* __restrict__ Wencbf,
                           ushortT* __restrict__ visbf, int* __restrict__ lens) {
  int bid = blockIdx.x, tid = threadIdx.x;
  if (bid < 16384) {
    int idx = bid * 256 + tid;
    int e = idx & 63, r = idx >> 6, b = r % B_, t = r / B_;
    ushortT ve = 0, vd = 0;
    if (e < E_) {
      int ie = text[b * L_ + t];
      int id = (t == 0) ? 0 : text[b * L_ + t - 1];
      ve = f2bf(emb[ie * E_ + e]);
      vd = f2bf(emb[id * E_ + e]);
    }
    xs_enc[idx] = ve; xs_dec[idx] = vd;
  } else if (bid < 16960) {                           // Wfrag: 32 slices x 18 ks x 4 ni x 64 ln
    int idx8 = (bid - 16384) * 256 + tid;
    int s = idx8 / 4608;
    int rem = idx8 - s * 4608;
    int ks = rem >> 8;
    int rem2 = rem & 255;
    int ni = rem2 >> 6, ln = rem2 & 63;
    int row = s * 64 + ni * 16 + (ln & 15);
    int kc = (ln >> 4) * 8;
    int j = row >> 2, qg = row & 3;
    int srow = qg * H_ + j;
    ushort8 val;
    if (ks < 16) {
      const float* src = W_hh + (size_t)srow * H_ + ks * 32 + kc;
#pragma unroll
      for (int x = 0; x < 8; ++x) val[x] = f2bf(src[x]);
    } else {
      int kb = (ks - 16) * 32 + kc;
#pragma unroll
      for (int x = 0; x < 8; ++x)
        val[x] = (kb + x < E_) ? f2bf(W_ih[(size_t)srow * E_ + kb + x]) : (ushortT)0;
    }
    *(ushort8*)(&Wfrag[(size_t)idx8 * 8]) = val;
  } else if (bid < 16992) {                           // Woutfrag
    int idx8 = (bid - 16960) * 256 + tid;
    int ks = idx8 >> 9;
    int rem = idx8 & 511;
    int nf = rem >> 6, ln = rem & 63;
    int row = nf * 16 + (ln & 15);
    int kc = ks * 32 + (ln >> 4) * 8;
    const float* src = W_out + (size_t)row * H_ + kc;
    ushort8 val;
#pragma unroll
    for (int x = 0; x < 8; ++x) val[x] = f2bf(src[x]);
    *(ushort8*)(&Woutfrag[(size_t)idx8 * 8]) = val;
  } else if (bid < 21088) {
    int idx = (bid - 16992) * 256 + tid;
    Wvisbf[idx] = f2bf(W_vis[idx]);
  } else if (bid < 22112) {
    int idx = (bid - 21088) * 256 + tid;
    Wencbf[idx] = f2bf(W_enc[idx]);
  } else if (bid < 30304) {
    int i = (bid - 22112) * 256 + tid;
    float4 v = ((const float4*)visual)[i];
    ushort4v o;
    o[0] = f2bf(v.x); o[1] = f2bf(v.y); o[2] = f2bf(v.z); o[3] = f2bf(v.w);
    ((ushort4v*)visbf)[i] = o;
  } else if (bid < 30320) {
    int b = (bid - 30304) * 256 + tid;
    int c = 0;
    for (int t = 0; t < L_; ++t) c += (text[b * L_ + t] != 0) ? 1 : 0;
    lens[b] = c;
  } else {                                            // biasc / biasc0, one wave per gate-row
    int wave = tid >> 6, lane = tid & 63;
    int p = (bid - 30320) * 4 + wave;
    int j = p >> 2, q = p & 3, o = q * H_ + j;
    const float* wr = W_hh + (size_t)o * H_;
    float rs = 0.f;
#pragma unroll
    for (int k = 0; k < H_ / 64; ++k) rs += wr[lane + k * 64];
#pragma unroll
    for (int d = 1; d < 64; d <<= 1) rs += __shfl_xor(rs, d);
    if (lane == 0) {
      float base = b_ih[o] + b_hh[o];
      biasc[p] = base;
      biasc0[p] = base + 0.1f * rs;
    }
  }
}

// ================================================================ gemm_ws2: 512 threads, 128x128 tile
__global__ __launch_bounds__(512, 2)
void gemm_ws2_k(const ushortT* __restrict__ A, int lda,
                const ushortT* __restrict__ Bp, int ldb, int kchunk,
                float* __restrict__ Cf, ushortT* __restrict__ Cb,
                int ldc, int Mtot) {
  __shared__ ushortT wl[2][16384];            // 2 x 32 KB
  const int tid = threadIdx.x;
  const int n0 = blockIdx.x * 128;
  const int m0 = blockIdx.y * 128;
  const int lane = tid & 63, wave = tid >> 6;
  const int q = lane >> 4, r = lane & 15;
  const int ak = q * 8;
  const int wrow = m0 + wave * 16;
  const int kbeg = blockIdx.z * kchunk;
  const int nchunks = kchunk >> 7;

  auto stage = [&](int kb, int buf) {
#pragma unroll
    for (int i = 0; i < 4; ++i) {
      int u = tid + i * 512;
      int f = u >> 6, l = u & 63;
      int kk = f >> 3, nn = f & 7;
      int row = n0 + nn * 16 + (l & 15);
      int kc = kb + kk * 32 + (l >> 4) * 8;
      *(ushort8*)(&wl[buf][((kk * 8 + nn) * 64 + l) * 8]) =
          *(const ushort8*)(&Bp[(size_t)row * ldb + kc]);
    }
  };

  f32x4 acc[8];
#pragma unroll
  for (int nn = 0; nn < 8; ++nn)
#pragma unroll
    for (int x = 0; x < 4; ++x) acc[nn][x] = 0.f;

  stage(kbeg, 0);
  __syncthreads();
  for (int ch = 0; ch < nchunks; ++ch) {
    int buf = ch & 1;
    if (ch + 1 < nchunks) stage(kbeg + (ch + 1) * 128, buf ^ 1);
    int kb = kbeg + ch * 128;
#pragma unroll
    for (int kk = 0; kk < 4; ++kk) {
      short8 a = *(const short8*)(&A[(size_t)(wrow + r) * lda + kb + kk * 32 + ak]);
#pragma unroll
      for (int nn = 0; nn < 8; ++nn) {
        short8 b = *(const short8*)(&wl[buf][((kk * 8 + nn) * 64 + lane) * 8]);
        acc[nn] = __builtin_amdgcn_mfma_f32_16x16x32_bf16(a, b, acc[nn], 0, 0, 0);
      }
    }
    __syncthreads();
  }

  if (Cb) {
#pragma unroll
    for (int nn = 0; nn < 8; ++nn) {
      int col = n0 + nn * 16 + r;
#pragma unroll
      for (int rr = 0; rr < 4; ++rr)
        Cb[(size_t)(wrow + q * 4 + rr) * ldc + col] = f2bf(acc[nn][rr]);
    }
  } else {
    float* Cz = Cf + (size_t)blockIdx.z * Mtot * ldc;
#pragma unroll
    for (int nn = 0; nn < 8; ++nn) {
      int col = n0 + nn * 16 + r;
#pragma unroll
      for (int rr = 0; rr < 4; ++rr)
        Cz[(size_t)(wrow + q * 4 + rr) * ldc + col] = acc[nn][rr];
    }
  }
}

// ================================================================ reduce partials + bias/relu + rownorm
__global__ void reduce_norm_k(const float* __restrict__ parts, int nparts,
                              const float* __restrict__ bias, int relu,
                              ushortT* __restrict__ outb, ushortT* __restrict__ outc) {
  int b = blockIdx.x, tid = threadIdx.x;
  float v[2];
  float ss = 0.f;
#pragma unroll
  for (int l = 0; l < 2; ++l) {
    int i = tid + l * 256;
    float s = 0.f;
    for (int p = 0; p < nparts; ++p)
      s += parts[(size_t)p * B_ * H_ + (size_t)b * H_ + i];
    if (bias) s += bias[i];
    if (relu) s = fmaxf(s, 0.f);
    v[l] = s;
    ss += s * s;
  }
  __shared__ float red[256];
  red[tid] = ss; __syncthreads();
  for (int st = 128; st > 0; st >>= 1) { if (tid < st) red[tid] += red[tid + st]; __syncthreads(); }
  float inv = 1.f / sqrtf(red[0]);
#pragma unroll
  for (int l = 0; l < 2; ++l) {
    int i = tid + l * 256;
    float x = v[l] * inv;
    ushortT xb = f2bf(x);
    outb[(size_t)b * H_ + i] = xb;
    if (outc) outc[(size_t)b * H_ + i] = xb;
  }
}

// ================================================================ LDS-free NLL for one 16-row unit;
// accumulates per-row (lse - target_logit) into lacc[4]; valid on all lanes of each quarter.
__device__ __forceinline__ void nll_step(const ushortT* __restrict__ h,
                                         const ushortT* __restrict__ Woutfrag,
                                         const int* __restrict__ text,
                                         int row0, int t, int lane, float* lacc) {
  const int q = lane >> 4, r = lane & 15;
  const int ak = q * 8;
  float m[4], s[4], tl[4];
  int tgt[4];
#pragma unroll
  for (int rr = 0; rr < 4; ++rr) {
    m[rr] = -1e30f; s[rr] = 0.f; tl[rr] = 0.f;
    tgt[rr] = text[(row0 + q * 4 + rr) * L_ + t];
  }
#pragma unroll
  for (int gg = 0; gg < 2; ++gg) {
    f32x4 acc[4];
#pragma unroll
    for (int nf = 0; nf < 4; ++nf)
#pragma unroll
      for (int x = 0; x < 4; ++x) acc[nf][x] = 0.f;
    for (int ks = 0; ks < 16; ++ks) {
      short8 a = *(const short8*)(&h[(size_t)(row0 + r) * H_ + ks * 32 + ak]);
#pragma unroll
      for (int nf = 0; nf < 4; ++nf) {
        short8 b = *(const short8*)(&Woutfrag[((ks * 8 + gg * 4 + nf) * 64 + lane) * 8]);
        acc[nf] = __builtin_amdgcn_mfma_f32_16x16x32_bf16(a, b, acc[nf], 0, 0, 0);
      }
    }
#pragma unroll
    for (int rr = 0; rr < 4; ++rr) {
      float gm = fmaxf(fmaxf(acc[0][rr], acc[1][rr]), fmaxf(acc[2][rr], acc[3][rr]));
      float nm = fmaxf(m[rr], gm);
      float sc = __expf(m[rr] - nm);
      s[rr] = s[rr] * sc + __expf(acc[0][rr] - nm) + __expf(acc[1][rr] - nm)
            + __expf(acc[2][rr] - nm) + __expf(acc[3][rr] - nm);
      m[rr] = nm;
      int tg = tgt[rr];
      if ((tg >> 6) == gg && r == (tg & 15)) {
        int nfl = (tg >> 4) & 3;
        float vv = (nfl == 0) ? acc[0][rr] : (nfl == 1) ? acc[1][rr]
                 : (nfl == 2) ? acc[2][rr] : acc[3][rr];
        tl[rr] = vv;
      }
    }
  }
#pragma unroll
  for (int rr = 0; rr < 4; ++rr) {
#pragma unroll
    for (int d = 1; d < 16; d <<= 1) {
      float om = __shfl_xor(m[rr], d);
      float os = __shfl_xor(s[rr], d);
      float M = fmaxf(m[rr], om);
      s[rr] = s[rr] * __expf(m[rr] - M) + os * __expf(om - M);
      m[rr] = M;
    }
    float lse = m[rr] + __logf(s[rr]);
    float tlb = __shfl(tl[rr], (lane & 48) + (tgt[rr] & 15));
    lacc[rr] += lse - tlb;
  }
}

// ================================================================ lstm7: round-0 structure + 48 KB LDS
// (3 blocks/CU), T14 async-stage split, XCD row pinning (blockIdx.x = row tile), NLL via
// one LDS-free extra block per row tile (blockIdx.y == 16).
__global__ __launch_bounds__(512, 6)
void lstm7_k(const ushortT* __restrict__ hin, const ushortT* __restrict__ Wfrag,
             const ushortT* __restrict__ xs, const float* __restrict__ biasc,
             ushortT* __restrict__ c, int cconst,
             ushortT* __restrict__ hout, ushortT* __restrict__ sel,
             const int* __restrict__ lens, int t,
             const ushortT* __restrict__ Woutfrag, const int* __restrict__ text,
             float* __restrict__ out, int losst) {
  __shared__ __align__(16) ushortT wl[2][12288];   // 2 x 24 KB
  const int tid = threadIdx.x;
  const int lane = tid & 63, wave = tid >> 6;
  const int q = lane >> 4, r = lane & 15;
  const int ak = q * 8;
  const int bx = blockIdx.x;                       // row tile 0..31 (XCD = bx % 8)
  const int by = blockIdx.y;                       // gate slice 0..15, or 16 = NLL
  const int m0 = bx * 128;

  if (by == 16) {
    // fused NLL on previous h (= hin) at losst: 8 waves x 16 rows = 128 rows
    int row0 = m0 + wave * 16;
    float lacc[4] = {0.f, 0.f, 0.f, 0.f};
    nll_step(hin, Woutfrag, text, row0, losst, lane, lacc);
#pragma unroll
    for (int rr = 0; rr < 4; ++rr) {
      if (r == 0) {
        int b = row0 + q * 4 + rr;
        float loss = lacc[rr] * (1.f / (float)L_);
        if (losst == 0) out[b] = loss;
        else out[b] += loss;
      }
    }
    return;
  }

  const int s2 = by;
  const int wrow = m0 + wave * 16;
  const ushortT* Wbase = Wfrag + (size_t)(2 * s2) * 36864;

  ushort8 wreg0, wreg1, wreg2;
  int su0, su1, su2;
  {
    int u0 = tid, u1 = tid + 512, u2 = tid + 1024;
    int f0 = u0 >> 6, f1 = u1 >> 6, f2 = u2 >> 6;
    su0 = (((f0 >> 3) * 8 + (f0 & 7)) * 64 + (u0 & 63)) * 8;
    su1 = (((f1 >> 3) * 8 + (f1 & 7)) * 64 + (u1 & 63)) * 8;
    su2 = (((f2 >> 3) * 8 + (f2 & 7)) * 64 + (u2 & 63)) * 8;
  }
  auto stage_load = [&](int chunk) {
#pragma unroll
    for (int i = 0; i < 3; ++i) {
      int u = tid + i * 512;
      int f = u >> 6, l = u & 63;
      int kk = f >> 3, nn = f & 7;
      int ks = chunk * 3 + kk;
      ushort8 v = *(const ushort8*)(Wbase + (size_t)(nn >> 2) * 36864 +
                                    ((size_t)(ks * 4 + (nn & 3)) * 64 + l) * 8);
      if (i == 0) wreg0 = v; else if (i == 1) wreg1 = v; else wreg2 = v;
    }
  };
  auto stage_write = [&](int buf) {
    *(ushort8*)(&wl[buf][su0]) = wreg0;
    *(ushort8*)(&wl[buf][su1]) = wreg1;
    *(ushort8*)(&wl[buf][su2]) = wreg2;
  };

  f32x4 acc[8];
#pragma unroll
  for (int nn = 0; nn < 8; ++nn)
#pragma unroll
    for (int x = 0; x < 4; ++x) acc[nn][x] = 0.f;

  const int cstart = hin ? 0 : 5;
  stage_load(cstart);
  stage_write(0);
  __syncthreads();
  for (int ch = cstart; ch < 6; ++ch) {
    const int buf = (ch - cstart) & 1;
    const bool pf = (ch < 5);
    if (pf) stage_load(ch + 1);              // issue-early: loads fly during MFMAs
    // A fragments for this chunk (L2-resident h/xs)
    short8 a0 = {}, a1, a2;
    const int ksb = ch * 3;
    const bool full = (hin != nullptr) || (ksb >= 16);
    if (full) {
      a0 = (ksb < 16) ? *(const short8*)(&hin[(size_t)(wrow + r) * H_ + ksb * 32 + ak])
                      : *(const short8*)(&xs[(size_t)(wrow + r) * EP_ + (ksb - 16) * 32 + ak]);
    }
    a1 = (ksb + 1 < 16) ? *(const short8*)(&hin[(size_t)(wrow + r) * H_ + (ksb + 1) * 32 + ak])
                        : *(const short8*)(&xs[(size_t)(wrow + r) * EP_ + (ksb + 1 - 16) * 32 + ak]);
    a2 = (ksb + 2 < 16) ? *(const short8*)(&hin[(size_t)(wrow + r) * H_ + (ksb + 2) * 32 + ak])
                        : *(const short8*)(&xs[(size_t)(wrow + r) * EP_ + (ksb + 2 - 16) * 32 + ak]);
#pragma unroll
    for (int nn = 0; nn < 8; ++nn) {
      if (full) {
        short8 b0 = *(const short8*)(&wl[buf][((0 * 8 + nn) * 64 + lane) * 8]);
        acc[nn] = __builtin_amdgcn_mfma_f32_16x16x32_bf16(a0, b0, acc[nn], 0, 0, 0);
      }
      short8 b1 = *(const short8*)(&wl[buf][((1 * 8 + nn) * 64 + lane) * 8]);
      acc[nn] = __builtin_amdgcn_mfma_f32_16x16x32_bf16(a1, b1, acc[nn], 0, 0, 0);
      short8 b2 = *(const short8*)(&wl[buf][((2 * 8 + nn) * 64 + lane) * 8]);
      acc[nn] = __builtin_amdgcn_mfma_f32_16x16x32_bf16(a2, b2, acc[nn], 0, 0, 0);
    }
    if (pf) {
      stage_write(buf ^ 1);                  // write-late: vmcnt drained after compute
      __syncthreads();
    }
  }

  // epilogue: shuffle-transpose + cell update; 16 rows x 128 gate-cols per wave
#pragma unroll
  for (int nn = 0; nn < 8; ++nn) {
    int row = wrow + q * 4 + (r & 3);
    float v0 = acc[nn][0], v1 = acc[nn][1], v2 = acc[nn][2], v3 = acc[nn][3];
    float s0 = __shfl_xor(v0, 2), s1 = __shfl_xor(v1, 2),
          s2s = __shfl_xor(v2, 2), s3 = __shfl_xor(v3, 2);
    float a0, a1, a2, a3;
    if (r & 2) { a0 = s2s; a1 = s3; a2 = v2; a3 = v3; }
    else       { a0 = v0; a1 = v1; a2 = s0; a3 = s1; }
    float t0 = __shfl_xor(a0, 1), t1 = __shfl_xor(a1, 1),
          t2 = __shfl_xor(a2, 1), t3 = __shfl_xor(a3, 1);
    float g0, g1, g2, g3;
    if (r & 1) { g0 = t1; g1 = a1; g2 = t3; g3 = a3; }
    else       { g0 = a0; g1 = t0; g2 = a2; g3 = t2; }
    int j = s2 * 32 + nn * 4 + (r >> 2);
    f32x4 bb = *(const f32x4*)(&biasc[j * 4]);
    float si = sigm(g0 + bb[0]);
    float sf = sigm(g1 + bb[1]);
    float tg = tanh_f(g2 + bb[2]);
    float so = sigm(g3 + bb[3]);
    size_t ci = (size_t)row * H_ + j;
    float cprev = cconst ? 0.1f : bf2f(c[ci]);
    float cn = sf * cprev + si * tg;
    float hn = so * tanh_f(cn);
    c[ci] = f2bf(cn);
    ushortT hb16 = f2bf(hn);
    hout[ci] = hb16;
    if (sel) {
      int len = lens[row];
      int eff = (len == 0) ? L_ : len;
      if (t == eff - 1) sel[ci] = hb16;
    }
  }
}

// ================================================================ standalone decoder loss (final step)
__global__ __launch_bounds__(256)
void dec_loss3_k(const ushortT* __restrict__ h, const ushortT* __restrict__ Woutfrag,
                 const int* __restrict__ text, int t, float* __restrict__ out) {
  __shared__ float pbuf[4 * 16 * 132];
  const int tid = threadIdx.x;
  const int row0 = blockIdx.x * 16;
  const int lane = tid & 63, wave = tid >> 6;
  const int am = lane & 15, ak = (lane >> 4) * 8;

  f32x4 acc[8];
#pragma unroll
  for (int i = 0; i < 8; ++i)
#pragma unroll
    for (int r = 0; r < 4; ++r) acc[i][r] = 0.f;

#pragma unroll
  for (int ks = 0; ks < 4; ++ks) {
    int ksg = wave * 4 + ks;
    short8 a = *(const short8*)(&h[(size_t)(row0 + am) * H_ + ksg * 32 + ak]);
#pragma unroll
    for (int nf = 0; nf < 8; ++nf) {
      short8 b = *(const short8*)(&Woutfrag[((ksg * 8 + nf) * 64 + lane) * 8]);
      acc[nf] = __builtin_amdgcn_mfma_f32_16x16x32_bf16(a, b, acc[nf], 0, 0, 0);
    }
  }
#pragma unroll
  for (int nf = 0; nf < 8; ++nf)
#pragma unroll
    for (int r = 0; r < 4; ++r) {
      int rowL = (lane >> 4) * 4 + r;
      pbuf[(wave * 16 + rowL) * 132 + nf * 16 + am] = acc[nf][r];
    }
  __syncthreads();

  int row = tid >> 4, lp = tid & 15;
  f32x4 s0, s1;
#pragma unroll
  for (int r = 0; r < 4; ++r) { s0[r] = 0.f; s1[r] = 0.f; }
#pragma unroll
  for (int wv = 0; wv < 4; ++wv) {
    s0 += *(const f32x4*)(&pbuf[(wv * 16 + row) * 132 + lp * 8]);
    s1 += *(const f32x4*)(&pbuf[(wv * 16 + row) * 132 + lp * 8 + 4]);
  }
  float mx = s0[0];
#pragma unroll
  for (int r = 1; r < 4; ++r) mx = fmaxf(mx, s0[r]);
#pragma unroll
  for (int r = 0; r < 4; ++r) mx = fmaxf(mx, s1[r]);
#pragma unroll
  for (int d = 1; d < 16; d <<= 1) mx = fmaxf(mx, __shfl_xor(mx, d));
  float sum = 0.f;
#pragma unroll
  for (int r = 0; r < 4; ++r) sum += __expf(s0[r] - mx) + __expf(s1[r] - mx);
#pragma unroll
  for (int d = 1; d < 16; d <<= 1) sum += __shfl_xor(sum, d);
  float lse = mx + __logf(sum);
  int b = row0 + row;
  int tgt = text[b * L_ + t];
  if ((tgt >> 3) == lp) {
    float lv = (tgt & 4) ? s1[tgt & 3] : s0[tgt & 3];
    float loss = (lse - lv) * (1.f / (float)L_);
    if (t == 0) out[b] = loss;
    else out[b] += loss;
  }
}

// ================================================================ softmax / transpose
__global__ __launch_bounds__(256)
void softmax_bf_rows_k(ushortT* __restrict__ P) {
  int rr = blockIdx.x, tid = threadIdx.x;
  ushortT* row = P + (size_t)rr * B_;
  float xv[16];
  float m = -1e30f;
#pragma unroll
  for (int l = 0; l < 16; ++l) { float v = bf2f(row[tid + l * 256]); xv[l] = v; m = fmaxf(m, v); }
  __shared__ float red[256];
  red[tid] = m; __syncthreads();
  for (int st = 128; st > 0; st >>= 1) { if (tid < st) red[tid] = fmaxf(red[tid], red[tid + st]); __syncthreads(); }
  m = red[0]; __syncthreads();
  float s = 0.f;
#pragma unroll
  for (int l = 0; l < 16; ++l) { float e = __expf(xv[l] - m); xv[l] = e; s += e; }
  red[tid] = s; __syncthreads();
  for (int st = 128; st > 0; st >>= 1) { if (tid < st) red[tid] += red[tid + st]; __syncthreads(); }
  float inv = 1.f / red[0];
#pragma unroll
  for (int l = 0; l < 16; ++l) row[tid + l * 256] = f2bf(xv[l] * inv);
}

__global__ void transpose_bf_k(const ushortT* __restrict__ in, ushortT* __restrict__ out,
                               int R, int Ccols) {
  __shared__ ushortT tile[32][33];
  int c0 = blockIdx.x * 32, r0 = blockIdx.y * 32;
  int tx = threadIdx.x & 31, ty = threadIdx.x >> 5;
  for (int i = ty; i < 32; i += 8) tile[i][tx] = in[(size_t)(r0 + i) * Ccols + c0 + tx];
  __syncthreads();
  for (int i = ty; i < 32; i += 8) out[(size_t)(c0 + i) * R + r0 + tx] = tile[tx][i];
}

// ================================================================ launch
extern "C" void kernel_launch(void* const* d_in, const int* in_sizes, int n_in,
                              void* d_out, int out_size, void* d_ws, size_t ws_size,
                              hipStream_t stream) {
  const float* visual = (const float*)d_in[0];
  const int*   text   = (const int*)  d_in[1];
  const float* emb    = (const float*)d_in[2];
  const float* W_ih   = (const float*)d_in[3];
  const float* W_hh   = (const float*)d_in[4];
  const float* b_ih   = (const float*)d_in[5];
  const float* b_hh   = (const float*)d_in[6];
  const float* W_enc  = (const float*)d_in[7];
  const float* b_enc  = (const float*)d_in[8];
  const float* W_out  = (const float*)d_in[9];
  const float* W_vis  = (const float*)d_in[10];
  float* out = (float*)d_out;

  char* w = (char*)d_ws;
  auto alloc = [&](size_t bytes) { char* p = w; w += (bytes + 255) & ~(size_t)255; return p; };
  ushortT* xs_enc   = (ushortT*)alloc((size_t)L_ * B_ * EP_ * 2);
  ushortT* xs_dec   = (ushortT*)alloc((size_t)L_ * B_ * EP_ * 2);
  ushortT* Wfrag    = (ushortT*)alloc((size_t)32 * 18 * 4 * 64 * 8 * 2);
  ushortT* Woutfrag = (ushortT*)alloc((size_t)16 * 8 * 64 * 8 * 2);
  float*   biasc    = (float*)  alloc((size_t)G4_ * 4);
  float*   biasc0   = (float*)  alloc((size_t)G4_ * 4);
  ushortT* Wvisbf   = (ushortT*)alloc((size_t)H_ * VIS_ * 2);
  ushortT* Wencbf   = (ushortT*)alloc((size_t)H_ * H_ * 2);
  ushortT* visbf    = (ushortT*)alloc((size_t)B_ * VIS_ * 2);
  ushortT* henc0    = (ushortT*)alloc((size_t)B_ * H_ * 2);
  ushortT* henc1    = (ushortT*)alloc((size_t)B_ * H_ * 2);
  ushortT* cenc     = (ushortT*)alloc((size_t)B_ * H_ * 2);
  ushortT* selbf    = (ushortT*)alloc((size_t)B_ * H_ * 2);
  ushortT* vbf      = (ushortT*)alloc((size_t)B_ * H_ * 2);
  ushortT* tencbf   = (ushortT*)alloc((size_t)B_ * H_ * 2);
  ushortT* Pbf      = (ushortT*)alloc((size_t)B_ * B_ * 2);
  ushortT* Vtbf     = (ushortT*)alloc((size_t)H_ * B_ * 2);
  ushortT* cdec     = (ushortT*)alloc((size_t)B_ * H_ * 2);
  ushortT* hdec0    = (ushortT*)alloc((size_t)B_ * H_ * 2);
  ushortT* hdec1    = (ushortT*)alloc((size_t)B_ * H_ * 2);
  int*     lens     = (int*)    alloc((size_t)B_ * 4);
  float*   parts    = (float*)  alloc((size_t)4 * B_ * H_ * 4);

  // ---- mega prep
  prep_all_k<<<dim3(30832), dim3(256), 0, stream>>>(
      visual, text, emb, W_ih, W_hh, b_ih, b_hh, W_enc, W_out, W_vis,
      xs_enc, xs_dec, Wfrag, Woutfrag, biasc, biasc0,
      Wvisbf, Wencbf, visbf, lens);

  // ---- visual projection (z=2, kchunk=1024) + rownorm -> vbf
  gemm_ws2_k<<<dim3(H_ / 128, B_ / 128, 2), dim3(512), 0, stream>>>(
      visbf, VIS_, Wvisbf, VIS_, 1024, parts, nullptr, H_, B_);
  reduce_norm_k<<<dim3(B_), dim3(256), 0, stream>>>(parts, 2, nullptr, 0, vbf, nullptr);

  // ---- encoder LSTM (t=0 folds h0 into biasc0)
  for (int t = 0; t < L_; ++t) {
    const ushortT* hin = (t == 0) ? nullptr : ((t & 1) ? henc1 : henc0);
    ushortT* hout = (t & 1) ? henc0 : henc1;
    lstm7_k<<<dim3(32, 16), dim3(512), 0, stream>>>(
        hin, Wfrag, xs_enc + (size_t)t * B_ * EP_,
        (t == 0) ? biasc0 : biasc, cenc, (t == 0) ? 1 : 0,
        hout, selbf, lens, t, nullptr, nullptr, nullptr, -1);
  }

  // ---- enc linear (z=2, kchunk=256) + bias/relu/rownorm -> tencbf
  gemm_ws2_k<<<dim3(H_ / 128, B_ / 128, 2), dim3(512), 0, stream>>>(
      selbf, H_, Wencbf, H_, 256, parts, nullptr, H_, B_);
  reduce_norm_k<<<dim3(B_), dim3(256), 0, stream>>>(parts, 2, b_enc, 1, tencbf, nullptr);

  // ---- attention
  gemm_ws2_k<<<dim3(B_ / 128, B_ / 128, 1), dim3(512), 0, stream>>>(
      tencbf, H_, vbf, H_, 512, nullptr, Pbf, B_, B_);
  softmax_bf_rows_k<<<dim3(B_), dim3(256), 0, stream>>>(Pbf);
  transpose_bf_k<<<dim3(H_ / 32, B_ / 32), dim3(256), 0, stream>>>(vbf, Vtbf, B_, H_);
  gemm_ws2_k<<<dim3(H_ / 128, B_ / 128, 4), dim3(512), 0, stream>>>(
      Pbf, B_, Vtbf, B_, 1024, parts, nullptr, H_, B_);
  reduce_norm_k<<<dim3(B_), dim3(256), 0, stream>>>(parts, 4, nullptr, 0, hdec0, cdec);

  // ---- decoder LSTM with fused previous-step NLL (t>=1), final NLL standalone
  for (int t = 0; t < L_; ++t) {
    const ushortT* hin = (t & 1) ? hdec1 : hdec0;
    ushortT* hout = (t & 1) ? hdec0 : hdec1;
    dim3 grid = (t > 0) ? dim3(32, 17) : dim3(32, 16);
    lstm7_k<<<grid, dim3(512), 0, stream>>>(
        hin, Wfrag, xs_dec + (size_t)t * B_ * EP_,
        biasc, cdec, 0, hout, nullptr, nullptr, t,
        Woutfrag, text, out, t - 1);
  }
  // h_15 lives in hdec0 (t=15 odd -> hout = hdec0)
  dec_loss3_k<<<dim3(B_ / 16), dim3(256), 0, stream>>>(hdec0, Woutfrag, text, L_ - 1, out);
}

// Round 4
// 967.788 us; speedup vs baseline: 2.5704x; 1.3719x over previous
//
#include <hip/hip_runtime.h>
#include <math.h>

#define B_    4096
#define L_    16
#define E_    50
#define EP_   64
#define H_    512
#define G4_   2048
#define V_    128
#define VIS_  2048

typedef unsigned short ushortT;
typedef ushortT ushort8 __attribute__((ext_vector_type(8)));
typedef ushortT ushort4v __attribute__((ext_vector_type(4)));
typedef short   short8  __attribute__((ext_vector_type(8)));
typedef float   f32x4   __attribute__((ext_vector_type(4)));

__device__ __forceinline__ ushortT f2bf(float f) {
  union { float f; unsigned u; } v; v.f = f;
  unsigned u = v.u;
  u += 0x7fffu + ((u >> 16) & 1u);
  return (ushortT)(u >> 16);
}
__device__ __forceinline__ float bf2f(ushortT h) {
  union { unsigned u; float f; } v; v.u = ((unsigned)h) << 16;
  return v.f;
}
__device__ __forceinline__ float sigm(float x) { return 1.f / (1.f + __expf(-x)); }
__device__ __forceinline__ float tanh_f(float x) { return 1.f - 2.f / (__expf(2.f * x) + 1.f); }

// async global->LDS, 16B per lane; lds dst is wave-uniform base (+lane*16 by HW)
__device__ __forceinline__ void glds16(const ushortT* g, ushortT* l) {
  __builtin_amdgcn_global_load_lds(
      (const __attribute__((address_space(1))) void*)g,
      (__attribute__((address_space(3))) void*)l, 16, 0, 0);
}

// ================================================================ mega prep (grid 30832 x 256)
__global__ void prep_all_k(const float* __restrict__ visual, const int* __restrict__ text,
                           const float* __restrict__ emb,
                           const float* __restrict__ W_ih, const float* __restrict__ W_hh,
                           const float* __restrict__ b_ih, const float* __restrict__ b_hh,
                           const float* __restrict__ W_enc, const float* __restrict__ W_out,
                           const float* __restrict__ W_vis,
                           ushortT* __restrict__ xs_enc, ushortT* __restrict__ xs_dec,
                           ushortT* __restrict__ Wfrag, ushortT* __restrict__ Woutfrag,
                           float* __restrict__ biasc, float* __restrict__ biasc0,
                           ushortT* __restrict__ Wvisbf, ushortT* __restrict__ Wencbf,
                           ushortT* __restrict__ visbf, int* __restrict__ lens) {
  int bid = blockIdx.x, tid = threadIdx.x;
  if (bid < 16384) {
    int idx = bid * 256 + tid;
    int e = idx & 63, r = idx >> 6, b = r % B_, t = r / B_;
    ushortT ve = 0, vd = 0;
    if (e < E_) {
      int ie = text[b * L_ + t];
      int id = (t == 0) ? 0 : text[b * L_ + t - 1];
      ve = f2bf(emb[ie * E_ + e]);
      vd = f2bf(emb[id * E_ + e]);
    }
    xs_enc[idx] = ve; xs_dec[idx] = vd;
  } else if (bid < 16960) {                           // Wfrag: 32 slices x 18 ks x 4 ni x 64 ln
    int idx8 = (bid - 16384) * 256 + tid;
    int s = idx8 / 4608;
    int rem = idx8 - s * 4608;
    int ks = rem >> 8;
    int rem2 = rem & 255;
    int ni = rem2 >> 6, ln = rem2 & 63;
    int row = s * 64 + ni * 16 + (ln & 15);
    int kc = (ln >> 4) * 8;
    int j = row >> 2, qg = row & 3;
    int srow = qg * H_ + j;
    ushort8 val;
    if (ks < 16) {
      const float* src = W_hh + (size_t)srow * H_ + ks * 32 + kc;
#pragma unroll
      for (int x = 0; x < 8; ++x) val[x] = f2bf(src[x]);
    } else {
      int kb = (ks - 16) * 32 + kc;
#pragma unroll
      for (int x = 0; x < 8; ++x)
        val[x] = (kb + x < E_) ? f2bf(W_ih[(size_t)srow * E_ + kb + x]) : (ushortT)0;
    }
    *(ushort8*)(&Wfrag[(size_t)idx8 * 8]) = val;
  } else if (bid < 16992) {                           // Woutfrag
    int idx8 = (bid - 16960) * 256 + tid;
    int ks = idx8 >> 9;
    int rem = idx8 & 511;
    int nf = rem >> 6, ln = rem & 63;
    int row = nf * 16 + (ln & 15);
    int kc = ks * 32 + (ln >> 4) * 8;
    const float* src = W_out + (size_t)row * H_ + kc;
    ushort8 val;
#pragma unroll
    for (int x = 0; x < 8; ++x) val[x] = f2bf(src[x]);
    *(ushort8*)(&Woutfrag[(size_t)idx8 * 8]) = val;
  } else if (bid < 21088) {
    int idx = (bid - 16992) * 256 + tid;
    Wvisbf[idx] = f2bf(W_vis[idx]);
  } else if (bid < 22112) {
    int idx = (bid - 21088) * 256 + tid;
    Wencbf[idx] = f2bf(W_enc[idx]);
  } else if (bid < 30304) {
    int i = (bid - 22112) * 256 + tid;
    float4 v = ((const float4*)visual)[i];
    ushort4v o;
    o[0] = f2bf(v.x); o[1] = f2bf(v.y); o[2] = f2bf(v.z); o[3] = f2bf(v.w);
    ((ushort4v*)visbf)[i] = o;
  } else if (bid < 30320) {
    int b = (bid - 30304) * 256 + tid;
    int c = 0;
    for (int t = 0; t < L_; ++t) c += (text[b * L_ + t] != 0) ? 1 : 0;
    lens[b] = c;
  } else {                                            // biasc / biasc0, one wave per gate-row
    int wave = tid >> 6, lane = tid & 63;
    int p = (bid - 30320) * 4 + wave;
    int j = p >> 2, q = p & 3, o = q * H_ + j;
    const float* wr = W_hh + (size_t)o * H_;
    float rs = 0.f;
#pragma unroll
    for (int k = 0; k < H_ / 64; ++k) rs += wr[lane + k * 64];
#pragma unroll
    for (int d = 1; d < 64; d <<= 1) rs += __shfl_xor(rs, d);
    if (lane == 0) {
      float base = b_ih[o] + b_hh[o];
      biasc[p] = base;
      biasc0[p] = base + 0.1f * rs;
    }
  }
}

// ================================================================ gemm_ws2: 512 threads, 128x128 tile
__global__ __launch_bounds__(512, 2)
void gemm_ws2_k(const ushortT* __restrict__ A, int lda,
                const ushortT* __restrict__ Bp, int ldb, int kchunk,
                float* __restrict__ Cf, ushortT* __restrict__ Cb,
                int ldc, int Mtot) {
  __shared__ ushortT wl[2][16384];            // 2 x 32 KB
  const int tid = threadIdx.x;
  const int n0 = blockIdx.x * 128;
  const int m0 = blockIdx.y * 128;
  const int lane = tid & 63, wave = tid >> 6;
  const int q = lane >> 4, r = lane & 15;
  const int ak = q * 8;
  const int wrow = m0 + wave * 16;
  const int kbeg = blockIdx.z * kchunk;
  const int nchunks = kchunk >> 7;

  auto stage = [&](int kb, int buf) {
#pragma unroll
    for (int i = 0; i < 4; ++i) {
      int u = tid + i * 512;
      int f = u >> 6, l = u & 63;
      int kk = f >> 3, nn = f & 7;
      int row = n0 + nn * 16 + (l & 15);
      int kc = kb + kk * 32 + (l >> 4) * 8;
      *(ushort8*)(&wl[buf][((kk * 8 + nn) * 64 + l) * 8]) =
          *(const ushort8*)(&Bp[(size_t)row * ldb + kc]);
    }
  };

  f32x4 acc[8];
#pragma unroll
  for (int nn = 0; nn < 8; ++nn)
#pragma unroll
    for (int x = 0; x < 4; ++x) acc[nn][x] = 0.f;

  stage(kbeg, 0);
  __syncthreads();
  for (int ch = 0; ch < nchunks; ++ch) {
    int buf = ch & 1;
    if (ch + 1 < nchunks) stage(kbeg + (ch + 1) * 128, buf ^ 1);
    int kb = kbeg + ch * 128;
#pragma unroll
    for (int kk = 0; kk < 4; ++kk) {
      short8 a = *(const short8*)(&A[(size_t)(wrow + r) * lda + kb + kk * 32 + ak]);
#pragma unroll
      for (int nn = 0; nn < 8; ++nn) {
        short8 b = *(const short8*)(&wl[buf][((kk * 8 + nn) * 64 + lane) * 8]);
        acc[nn] = __builtin_amdgcn_mfma_f32_16x16x32_bf16(a, b, acc[nn], 0, 0, 0);
      }
    }
    __syncthreads();
  }

  if (Cb) {
#pragma unroll
    for (int nn = 0; nn < 8; ++nn) {
      int col = n0 + nn * 16 + r;
#pragma unroll
      for (int rr = 0; rr < 4; ++rr)
        Cb[(size_t)(wrow + q * 4 + rr) * ldc + col] = f2bf(acc[nn][rr]);
    }
  } else {
    float* Cz = Cf + (size_t)blockIdx.z * Mtot * ldc;
#pragma unroll
    for (int nn = 0; nn < 8; ++nn) {
      int col = n0 + nn * 16 + r;
#pragma unroll
      for (int rr = 0; rr < 4; ++rr)
        Cz[(size_t)(wrow + q * 4 + rr) * ldc + col] = acc[nn][rr];
    }
  }
}

// ================================================================ reduce partials + bias/relu + rownorm
__global__ void reduce_norm_k(const float* __restrict__ parts, int nparts,
                              const float* __restrict__ bias, int relu,
                              ushortT* __restrict__ outb, ushortT* __restrict__ outc) {
  int b = blockIdx.x, tid = threadIdx.x;
  float v[2];
  float ss = 0.f;
#pragma unroll
  for (int l = 0; l < 2; ++l) {
    int i = tid + l * 256;
    float s = 0.f;
    for (int p = 0; p < nparts; ++p)
      s += parts[(size_t)p * B_ * H_ + (size_t)b * H_ + i];
    if (bias) s += bias[i];
    if (relu) s = fmaxf(s, 0.f);
    v[l] = s;
    ss += s * s;
  }
  __shared__ float red[256];
  red[tid] = ss; __syncthreads();
  for (int st = 128; st > 0; st >>= 1) { if (tid < st) red[tid] += red[tid + st]; __syncthreads(); }
  float inv = 1.f / sqrtf(red[0]);
#pragma unroll
  for (int l = 0; l < 2; ++l) {
    int i = tid + l * 256;
    float x = v[l] * inv;
    ushortT xb = f2bf(x);
    outb[(size_t)b * H_ + i] = xb;
    if (outc) outc[(size_t)b * H_ + i] = xb;
  }
}

// ================================================================ lstm8: round-0 lstm5 structure,
// 1-D grid with XCD row-pinning swizzle + global_load_lds(16B) staging. Grid 512 (+128 NLL).
__global__ __launch_bounds__(512, 2)
void lstm8_k(const ushortT* __restrict__ hin, const ushortT* __restrict__ Wfrag,
             const ushortT* __restrict__ xs, const float* __restrict__ biasc,
             ushortT* __restrict__ c, int cconst,
             ushortT* __restrict__ hout, ushortT* __restrict__ sel,
             const int* __restrict__ lens, int t,
             const ushortT* __restrict__ Woutfrag, const int* __restrict__ text,
             float* __restrict__ out, int losst) {
  __shared__ char smem[67584];
  const int tid = threadIdx.x;
  const int lane = tid & 63, wave = tid >> 6;
  const int q = lane >> 4, r = lane & 15;
  const int ak = q * 8;
  const int fid = blockIdx.x;

  if (fid >= 512) {
    // fused NLL for previous step's h (= hin); two 4-wave groups x 16 rows; 32 rows/block.
    // id->rows swizzle keeps XCD (fid%8) == row-tile%8, matching the GEMM pinning.
    float* pbuf = (float*)smem;
    const int u0 = fid - 512;                        // 0..127
    const int rt = (u0 & 7) + 8 * ((u0 >> 3) & 3);   // row tile 0..31, rt%8 == u0%8
    const int base = rt * 128 + (u0 >> 5) * 32;
    const int group = wave >> 2, wv = wave & 3;
    float* pbase = pbuf + group * 8448;
    const int row0g = base + group * 16;
    f32x4 dacc[8];
#pragma unroll
    for (int i = 0; i < 8; ++i)
#pragma unroll
      for (int x = 0; x < 4; ++x) dacc[i][x] = 0.f;
#pragma unroll
    for (int ks = 0; ks < 4; ++ks) {
      int ksg = wv * 4 + ks;
      short8 a = *(const short8*)(&hin[(size_t)(row0g + r) * H_ + ksg * 32 + ak]);
#pragma unroll
      for (int nf = 0; nf < 8; ++nf) {
        short8 b = *(const short8*)(&Woutfrag[((ksg * 8 + nf) * 64 + lane) * 8]);
        dacc[nf] = __builtin_amdgcn_mfma_f32_16x16x32_bf16(a, b, dacc[nf], 0, 0, 0);
      }
    }
#pragma unroll
    for (int nf = 0; nf < 8; ++nf)
#pragma unroll
      for (int rr = 0; rr < 4; ++rr)
        pbase[(wv * 16 + q * 4 + rr) * 132 + nf * 16 + r] = dacc[nf][rr];
    __syncthreads();
    int g = tid & 255;
    int grp2 = tid >> 8;
    float* pb2 = pbuf + grp2 * 8448;
    int row = g >> 4, lp = g & 15;
    f32x4 s0, s1;
#pragma unroll
    for (int rr = 0; rr < 4; ++rr) { s0[rr] = 0.f; s1[rr] = 0.f; }
#pragma unroll
    for (int wv2 = 0; wv2 < 4; ++wv2) {
      s0 += *(const f32x4*)(&pb2[(wv2 * 16 + row) * 132 + lp * 8]);
      s1 += *(const f32x4*)(&pb2[(wv2 * 16 + row) * 132 + lp * 8 + 4]);
    }
    float mx = s0[0];
#pragma unroll
    for (int rr = 1; rr < 4; ++rr) mx = fmaxf(mx, s0[rr]);
#pragma unroll
    for (int rr = 0; rr < 4; ++rr) mx = fmaxf(mx, s1[rr]);
#pragma unroll
    for (int d = 1; d < 16; d <<= 1) mx = fmaxf(mx, __shfl_xor(mx, d));
    float sum = 0.f;
#pragma unroll
    for (int rr = 0; rr < 4; ++rr) sum += __expf(s0[rr] - mx) + __expf(s1[rr] - mx);
#pragma unroll
    for (int d = 1; d < 16; d <<= 1) sum += __shfl_xor(sum, d);
    float lse = mx + __logf(sum);
    int b = base + grp2 * 16 + row;
    int tgt = text[b * L_ + losst];
    if ((tgt >> 3) == lp) {
      float lv = (tgt & 4) ? s1[tgt & 3] : s0[tgt & 3];
      float loss = (lse - lv) * (1.f / (float)L_);
      if (losst == 0) out[b] = loss;
      else out[b] += loss;
    }
    return;
  }

  // LSTM gate GEMM + cell update; XCD pinning: row tile rt has rt%8 == fid%8 for all 16 slices
  ushortT* wl = (ushortT*)smem;
  const int rt = (fid & 7) + 8 * ((fid >> 3) & 3);   // row tile 0..31
  const int s2 = fid >> 5;                           // gate slice 0..15
  const int m0 = rt * 128;
  const int wrow = m0 + wave * 16;
  const ushortT* Wbase = Wfrag + (size_t)(2 * s2) * 36864;

  // async stage: per wave, 3 x (64 lanes x 16B) = 3 KB; 8 waves cover the 24 KB chunk.
  // LDS layout identical to round-0; dst is the wave-uniform lane-0 base.
  auto stage = [&](int chunk, int buf) {
#pragma unroll
    for (int i = 0; i < 3; ++i) {
      int f = wave + i * 8;                          // 0..23
      int kk = f >> 3, nn = f & 7;
      int ks = chunk * 3 + kk;
      const ushortT* src = Wbase + (size_t)(nn >> 2) * 36864 +
                           ((size_t)(ks * 4 + (nn & 3)) * 64 + lane) * 8;
      ushortT* dst = wl + (size_t)buf * 12288 + (size_t)((kk * 8 + nn) * 64) * 8;
      glds16(src, dst);
    }
  };

  f32x4 acc[8];
#pragma unroll
  for (int nn = 0; nn < 8; ++nn)
#pragma unroll
    for (int x = 0; x < 4; ++x) acc[nn][x] = 0.f;

  const int cstart = hin ? 0 : 5;
  stage(cstart, 0);
  __syncthreads();
  for (int ch = cstart; ch < 6; ++ch) {
    int buf = (ch - cstart) & 1;
    if (ch < 5) stage(ch + 1, buf ^ 1);     // fire-and-forget; drained by end-of-chunk barrier
#pragma unroll
    for (int kk = 0; kk < 3; ++kk) {
      int ks = ch * 3 + kk;
      if (!hin && ks < 16) continue;
      short8 a;
      if (ks < 16) a = *(const short8*)(&hin[(size_t)(wrow + r) * H_ + ks * 32 + ak]);
      else         a = *(const short8*)(&xs[(size_t)(wrow + r) * EP_ + (ks - 16) * 32 + ak]);
#pragma unroll
      for (int nn = 0; nn < 8; ++nn) {
        short8 b = *(const short8*)(&wl[(size_t)buf * 12288 + ((kk * 8 + nn) * 64 + lane) * 8]);
        acc[nn] = __builtin_amdgcn_mfma_f32_16x16x32_bf16(a, b, acc[nn], 0, 0, 0);
      }
    }
    __syncthreads();
  }

  // epilogue: shuffle-transpose + cell update; 16 rows x 128 cols per wave
#pragma unroll
  for (int nn = 0; nn < 8; ++nn) {
    int row = wrow + q * 4 + (r & 3);
    float v0 = acc[nn][0], v1 = acc[nn][1], v2 = acc[nn][2], v3 = acc[nn][3];
    float s0 = __shfl_xor(v0, 2), s1 = __shfl_xor(v1, 2),
          s2s = __shfl_xor(v2, 2), s3 = __shfl_xor(v3, 2);
    float a0, a1, a2, a3;
    if (r & 2) { a0 = s2s; a1 = s3; a2 = v2; a3 = v3; }
    else       { a0 = v0; a1 = v1; a2 = s0; a3 = s1; }
    float t0 = __shfl_xor(a0, 1), t1 = __shfl_xor(a1, 1),
          t2 = __shfl_xor(a2, 1), t3 = __shfl_xor(a3, 1);
    float g0, g1, g2, g3;
    if (r & 1) { g0 = t1; g1 = a1; g2 = t3; g3 = a3; }
    else       { g0 = a0; g1 = t0; g2 = a2; g3 = t2; }
    int j = s2 * 32 + nn * 4 + (r >> 2);
    f32x4 bb = *(const f32x4*)(&biasc[j * 4]);
    float si = sigm(g0 + bb[0]);
    float sf = sigm(g1 + bb[1]);
    float tg = tanh_f(g2 + bb[2]);
    float so = sigm(g3 + bb[3]);
    size_t ci = (size_t)row * H_ + j;
    float cprev = cconst ? 0.1f : bf2f(c[ci]);
    float cn = sf * cprev + si * tg;
    float hn = so * tanh_f(cn);
    c[ci] = f2bf(cn);
    ushortT hb16 = f2bf(hn);
    hout[ci] = hb16;
    if (sel) {
      int len = lens[row];
      int eff = (len == 0) ? L_ : len;
      if (t == eff - 1) sel[ci] = hb16;
    }
  }
}

// ================================================================ standalone decoder loss (final step)
__global__ __launch_bounds__(256)
void dec_loss3_k(const ushortT* __restrict__ h, const ushortT* __restrict__ Woutfrag,
                 const int* __restrict__ text, int t, float* __restrict__ out) {
  __shared__ float pbuf[4 * 16 * 132];
  const int tid = threadIdx.x;
  const int row0 = blockIdx.x * 16;
  const int lane = tid & 63, wave = tid >> 6;
  const int am = lane & 15, ak = (lane >> 4) * 8;

  f32x4 acc[8];
#pragma unroll
  for (int i = 0; i < 8; ++i)
#pragma unroll
    for (int r = 0; r < 4; ++r) acc[i][r] = 0.f;

#pragma unroll
  for (int ks = 0; ks < 4; ++ks) {
    int ksg = wave * 4 + ks;
    short8 a = *(const short8*)(&h[(size_t)(row0 + am) * H_ + ksg * 32 + ak]);
#pragma unroll
    for (int nf = 0; nf < 8; ++nf) {
      short8 b = *(const short8*)(&Woutfrag[((ksg * 8 + nf) * 64 + lane) * 8]);
      acc[nf] = __builtin_amdgcn_mfma_f32_16x16x32_bf16(a, b, acc[nf], 0, 0, 0);
    }
  }
#pragma unroll
  for (int nf = 0; nf < 8; ++nf)
#pragma unroll
    for (int r = 0; r < 4; ++r) {
      int rowL = (lane >> 4) * 4 + r;
      pbuf[(wave * 16 + rowL) * 132 + nf * 16 + am] = acc[nf][r];
    }
  __syncthreads();

  int row = tid >> 4, lp = tid & 15;
  f32x4 s0, s1;
#pragma unroll
  for (int r = 0; r < 4; ++r) { s0[r] = 0.f; s1[r] = 0.f; }
#pragma unroll
  for (int wv = 0; wv < 4; ++wv) {
    s0 += *(const f32x4*)(&pbuf[(wv * 16 + row) * 132 + lp * 8]);
    s1 += *(const f32x4*)(&pbuf[(wv * 16 + row) * 132 + lp * 8 + 4]);
  }
  float mx = s0[0];
#pragma unroll
  for (int r = 1; r < 4; ++r) mx = fmaxf(mx, s0[r]);
#pragma unroll
  for (int r = 0; r < 4; ++r) mx = fmaxf(mx, s1[r]);
#pragma unroll
  for (int d = 1; d < 16; d <<= 1) mx = fmaxf(mx, __shfl_xor(mx, d));
  float sum = 0.f;
#pragma unroll
  for (int r = 0; r < 4; ++r) sum += __expf(s0[r] - mx) + __expf(s1[r] - mx);
#pragma unroll
  for (int d = 1; d < 16; d <<= 1) sum += __shfl_xor(sum, d);
  float lse = mx + __logf(sum);
  int b = row0 + row;
  int tgt = text[b * L_ + t];
  if ((tgt >> 3) == lp) {
    float lv = (tgt & 4) ? s1[tgt & 3] : s0[tgt & 3];
    float loss = (lse - lv) * (1.f / (float)L_);
    if (t == 0) out[b] = loss;
    else out[b] += loss;
  }
}

// ================================================================ softmax / transpose
__global__ __launch_bounds__(256)
void softmax_bf_rows_k(ushortT* __restrict__ P) {
  int rr = blockIdx.x, tid = threadIdx.x;
  ushortT* row = P + (size_t)rr * B_;
  float xv[16];
  float m = -1e30f;
#pragma unroll
  for (int l = 0; l < 16; ++l) { float v = bf2f(row[tid + l * 256]); xv[l] = v; m = fmaxf(m, v); }
  __shared__ float red[256];
  red[tid] = m; __syncthreads();
  for (int st = 128; st > 0; st >>= 1) { if (tid < st) red[tid] = fmaxf(red[tid], red[tid + st]); __syncthreads(); }
  m = red[0]; __syncthreads();
  float s = 0.f;
#pragma unroll
  for (int l = 0; l < 16; ++l) { float e = __expf(xv[l] - m); xv[l] = e; s += e; }
  red[tid] = s; __syncthreads();
  for (int st = 128; st > 0; st >>= 1) { if (tid < st) red[tid] += red[tid + st]; __syncthreads(); }
  float inv = 1.f / red[0];
#pragma unroll
  for (int l = 0; l < 16; ++l) row[tid + l * 256] = f2bf(xv[l] * inv);
}

__global__ void transpose_bf_k(const ushortT* __restrict__ in, ushortT* __restrict__ out,
                               int R, int Ccols) {
  __shared__ ushortT tile[32][33];
  int c0 = blockIdx.x * 32, r0 = blockIdx.y * 32;
  int tx = threadIdx.x & 31, ty = threadIdx.x >> 5;
  for (int i = ty; i < 32; i += 8) tile[i][tx] = in[(size_t)(r0 + i) * Ccols + c0 + tx];
  __syncthreads();
  for (int i = ty; i < 32; i += 8) out[(size_t)(c0 + i) * R + r0 + tx] = tile[tx][i];
}

// ================================================================ launch
extern "C" void kernel_launch(void* const* d_in, const int* in_sizes, int n_in,
                              void* d_out, int out_size, void* d_ws, size_t ws_size,
                              hipStream_t stream) {
  const float* visual = (const float*)d_in[0];
  const int*   text   = (const int*)  d_in[1];
  const float* emb    = (const float*)d_in[2];
  const float* W_ih   = (const float*)d_in[3];
  const float* W_hh   = (const float*)d_in[4];
  const float* b_ih   = (const float*)d_in[5];
  const float* b_hh   = (const float*)d_in[6];
  const float* W_enc  = (const float*)d_in[7];
  const float* b_enc  = (const float*)d_in[8];
  const float* W_out  = (const float*)d_in[9];
  const float* W_vis  = (const float*)d_in[10];
  float* out = (float*)d_out;

  char* w = (char*)d_ws;
  auto alloc = [&](size_t bytes) { char* p = w; w += (bytes + 255) & ~(size_t)255; return p; };
  ushortT* xs_enc   = (ushortT*)alloc((size_t)L_ * B_ * EP_ * 2);
  ushortT* xs_dec   = (ushortT*)alloc((size_t)L_ * B_ * EP_ * 2);
  ushortT* Wfrag    = (ushortT*)alloc((size_t)32 * 18 * 4 * 64 * 8 * 2);
  ushortT* Woutfrag = (ushortT*)alloc((size_t)16 * 8 * 64 * 8 * 2);
  float*   biasc    = (float*)  alloc((size_t)G4_ * 4);
  float*   biasc0   = (float*)  alloc((size_t)G4_ * 4);
  ushortT* Wvisbf   = (ushortT*)alloc((size_t)H_ * VIS_ * 2);
  ushortT* Wencbf   = (ushortT*)alloc((size_t)H_ * H_ * 2);
  ushortT* visbf    = (ushortT*)alloc((size_t)B_ * VIS_ * 2);
  ushortT* henc0    = (ushortT*)alloc((size_t)B_ * H_ * 2);
  ushortT* henc1    = (ushortT*)alloc((size_t)B_ * H_ * 2);
  ushortT* cenc     = (ushortT*)alloc((size_t)B_ * H_ * 2);
  ushortT* selbf    = (ushortT*)alloc((size_t)B_ * H_ * 2);
  ushortT* vbf      = (ushortT*)alloc((size_t)B_ * H_ * 2);
  ushortT* tencbf   = (ushortT*)alloc((size_t)B_ * H_ * 2);
  ushortT* Pbf      = (ushortT*)alloc((size_t)B_ * B_ * 2);
  ushortT* Vtbf     = (ushortT*)alloc((size_t)H_ * B_ * 2);
  ushortT* cdec     = (ushortT*)alloc((size_t)B_ * H_ * 2);
  ushortT* hdec0    = (ushortT*)alloc((size_t)B_ * H_ * 2);
  ushortT* hdec1    = (ushortT*)alloc((size_t)B_ * H_ * 2);
  int*     lens     = (int*)    alloc((size_t)B_ * 4);
  float*   parts    = (float*)  alloc((size_t)4 * B_ * H_ * 4);

  // ---- mega prep
  prep_all_k<<<dim3(30832), dim3(256), 0, stream>>>(
      visual, text, emb, W_ih, W_hh, b_ih, b_hh, W_enc, W_out, W_vis,
      xs_enc, xs_dec, Wfrag, Woutfrag, biasc, biasc0,
      Wvisbf, Wencbf, visbf, lens);

  // ---- visual projection (z=2, kchunk=1024) + rownorm -> vbf
  gemm_ws2_k<<<dim3(H_ / 128, B_ / 128, 2), dim3(512), 0, stream>>>(
      visbf, VIS_, Wvisbf, VIS_, 1024, parts, nullptr, H_, B_);
  reduce_norm_k<<<dim3(B_), dim3(256), 0, stream>>>(parts, 2, nullptr, 0, vbf, nullptr);

  // ---- encoder LSTM (t=0 folds h0 into biasc0)
  for (int t = 0; t < L_; ++t) {
    const ushortT* hin = (t == 0) ? nullptr : ((t & 1) ? henc1 : henc0);
    ushortT* hout = (t & 1) ? henc0 : henc1;
    lstm8_k<<<dim3(512), dim3(512), 0, stream>>>(
        hin, Wfrag, xs_enc + (size_t)t * B_ * EP_,
        (t == 0) ? biasc0 : biasc, cenc, (t == 0) ? 1 : 0,
        hout, selbf, lens, t, nullptr, nullptr, nullptr, -1);
  }

  // ---- enc linear (z=2, kchunk=256) + bias/relu/rownorm -> tencbf
  gemm_ws2_k<<<dim3(H_ / 128, B_ / 128, 2), dim3(512), 0, stream>>>(
      selbf, H_, Wencbf, H_, 256, parts, nullptr, H_, B_);
  reduce_norm_k<<<dim3(B_), dim3(256), 0, stream>>>(parts, 2, b_enc, 1, tencbf, nullptr);

  // ---- attention
  gemm_ws2_k<<<dim3(B_ / 128, B_ / 128, 1), dim3(512), 0, stream>>>(
      tencbf, H_, vbf, H_, 512, nullptr, Pbf, B_, B_);
  softmax_bf_rows_k<<<dim3(B_), dim3(256), 0, stream>>>(Pbf);
  transpose_bf_k<<<dim3(H_ / 32, B_ / 32), dim3(256), 0, stream>>>(vbf, Vtbf, B_, H_);
  gemm_ws2_k<<<dim3(H_ / 128, B_ / 128, 4), dim3(512), 0, stream>>>(
      Pbf, B_, Vtbf, B_, 1024, parts, nullptr, H_, B_);
  reduce_norm_k<<<dim3(B_), dim3(256), 0, stream>>>(parts, 4, nullptr, 0, hdec0, cdec);

  // ---- decoder LSTM with fused previous-step NLL (t>=1), final NLL standalone
  for (int t = 0; t < L_; ++t) {
    const ushortT* hin = (t & 1) ? hdec1 : hdec0;
    ushortT* hout = (t & 1) ? hdec0 : hdec1;
    dim3 grid = (t > 0) ? dim3(640) : dim3(512);
    lstm8_k<<<grid, dim3(512), 0, stream>>>(
        hin, Wfrag, xs_dec + (size_t)t * B_ * EP_,
        biasc, cdec, 0, hout, nullptr, nullptr, t,
        Woutfrag, text, out, t - 1);
  }
  // h_15 lives in hdec0 (t=15 odd -> hout = hdec0)
  dec_loss3_k<<<dim3(B_ / 16), dim3(256), 0, stream>>>(hdec0, Woutfrag, text, L_ - 1, out);
}